// Round 12
// baseline (173.783 us; speedup 1.0000x reference)
//
#include <hip/hip_runtime.h>
#include <hip/hip_fp16.h>
#include <math.h>

#define NF 32

typedef _Float16 half8 __attribute__((ext_vector_type(8)));
typedef float f32x4 __attribute__((ext_vector_type(4)));

__device__ __forceinline__ void atomic_pk_add_f16(unsigned int* addr, unsigned int val) {
    asm volatile("global_atomic_pk_add_f16 %0, %1, off" :: "v"(addr), "v"(val) : "memory");
}

// ---- kernel 1: out-degree by src; also zeroes acc --------------------------
__global__ __launch_bounds__(256) void count_kernel(const int* __restrict__ src,
                                                    int* __restrict__ cnt,
                                                    unsigned int* __restrict__ acc,
                                                    int E, int NT) {
    int e = blockIdx.x * blockDim.x + threadIdx.x;
    if (e < NT) acc[e] = 0u;
    if (e < E) atomicAdd(&cnt[src[e]], 1);
}

// ---- kernel 2: scatter acc[dst] += f16x2(rsqrt(cnt[src]) * x[src]) ---------
__global__ __launch_bounds__(256) void scatter_kernel(
    const int* __restrict__ src, const int* __restrict__ dst,
    const int* __restrict__ cnt, const float* __restrict__ x,
    unsigned int* __restrict__ acc, int E) {
    int t = blockIdx.x * blockDim.x + threadIdx.x;
    int e = t >> 4;
    int f2 = t & 15;
    if (e >= E) return;
    int s = src[e];
    int d = dst[e];
    float di = rsqrtf((float)cnt[s]);
    float2 xv = *(const float2*)(x + (size_t)s * NF + f2 * 2);
    unsigned short lo = __half_as_ushort(__float2half(di * xv.x));
    unsigned short hi = __half_as_ushort(__float2half(di * xv.y));
    atomic_pk_add_f16(&acc[(size_t)d * 16 + f2], ((unsigned int)hi << 16) | lo);
}

// ---- kernel 3: MFMA gates + readout (grid-stride, LDS-staged transposed W) -
// 256 threads = 4 waves; each wave owns 16-node tiles strided by gridDim*4.
#define GATE_BLOCKS 512
__global__ __launch_bounds__(256) void gate_kernel(
    const float* __restrict__ x, const unsigned short* __restrict__ acc16,
    const int* __restrict__ cnt,
    const float* __restrict__ Wxz0, const float* __restrict__ Wxz1,
    const float* __restrict__ bxz,  const float* __restrict__ bhz,
    const float* __restrict__ Wxh0, const float* __restrict__ Wxh1,
    const float* __restrict__ bxh,  const float* __restrict__ bhh,
    const float* __restrict__ Wl,   const float* __restrict__ bl,
    float* __restrict__ out, int N)
{
    // transposed weights: sWT[mat][c][k] = Wmat[k][c]; pad k-dim to 33
    __shared__ float sWT[4][NF][NF + 1];

    int t = threadIdx.x;
    for (int i = t; i < 4 * NF * NF; i += 256) {
        int m   = i >> 10;
        int idx = i & 1023;
        int k   = idx >> 5;
        int c   = idx & 31;
        const float* W = (m == 0) ? Wxz0 : (m == 1) ? Wxz1 : (m == 2) ? Wxh0 : Wxh1;
        sWT[m][c][k] = W[k * NF + c];
    }
    __syncthreads();

    int lane = t & 63;
    int wv   = t >> 6;
    int col  = lane & 15;       // B-frag col / A-frag row index
    int g    = lane >> 4;       // k-group: lane's k slots = g*8 .. g*8+7

    // --- per-lane W fragments from LDS (2 x ds_read_b128 each) --------------
    half8 bz0[2], bz1[2], bh0[2], bh1[2];
    #pragma unroll
    for (int h = 0; h < 2; ++h) {
        int c = col + 16 * h;
        #pragma unroll
        for (int m = 0; m < 4; ++m) {
            const float4* p = (const float4*)&sWT[m][c][g * 8];
            float4 a = p[0], b = p[1];
            half8 fr;
            fr[0] = (_Float16)a.x; fr[1] = (_Float16)a.y;
            fr[2] = (_Float16)a.z; fr[3] = (_Float16)a.w;
            fr[4] = (_Float16)b.x; fr[5] = (_Float16)b.y;
            fr[6] = (_Float16)b.z; fr[7] = (_Float16)b.w;
            if (m == 0) bz0[h] = fr; else if (m == 1) bz1[h] = fr;
            else if (m == 2) bh0[h] = fr; else bh1[h] = fr;
        }
    }
    float bz_c[2], bh_c[2], wl_c[2];
    #pragma unroll
    for (int h = 0; h < 2; ++h) {
        int c = col + 16 * h;
        bz_c[h] = bxz[c] + bhz[c];
        bh_c[h] = bxh[c] + bhh[c];
        wl_c[h] = Wl[c];
    }
    float bl0 = bl[0];

    int ntiles = (N + 15) >> 4;
    for (int tile = blockIdx.x * 4 + wv; tile < ntiles; tile += GATE_BLOCKS * 4) {
        int tile0 = tile << 4;

        // A fragments: row = tile0+col, k slots g*8..g*8+7
        int row = tile0 + col;
        int rc  = (row < N) ? row : (N - 1);
        const float* xr = x + (size_t)rc * NF + g * 8;
        float4 xa = *(const float4*)xr;
        float4 xb = *(const float4*)(xr + 4);
        half8 ax;
        ax[0] = (_Float16)xa.x; ax[1] = (_Float16)xa.y;
        ax[2] = (_Float16)xa.z; ax[3] = (_Float16)xa.w;
        ax[4] = (_Float16)xb.x; ax[5] = (_Float16)xb.y;
        ax[6] = (_Float16)xb.z; ax[7] = (_Float16)xb.w;

        int dg = cnt[rc];
        float mdn = (dg > 0) ? -rsqrtf((float)dg) : 0.0f;
        uint4 av = *(const uint4*)(acc16 + (size_t)rc * NF + g * 8);
        half8 at;
        {
            __half2 p;
            p = *(__half2*)&av.x; at[0] = (_Float16)(mdn * __half2float(p.x)); at[1] = (_Float16)(mdn * __half2float(p.y));
            p = *(__half2*)&av.y; at[2] = (_Float16)(mdn * __half2float(p.x)); at[3] = (_Float16)(mdn * __half2float(p.y));
            p = *(__half2*)&av.z; at[4] = (_Float16)(mdn * __half2float(p.x)); at[5] = (_Float16)(mdn * __half2float(p.y));
            p = *(__half2*)&av.w; at[6] = (_Float16)(mdn * __half2float(p.x)); at[7] = (_Float16)(mdn * __half2float(p.y));
        }

        f32x4 az[2], ah[2];
        #pragma unroll
        for (int h = 0; h < 2; ++h) {
            az[h] = (f32x4){bz_c[h], bz_c[h], bz_c[h], bz_c[h]};
            ah[h] = (f32x4){bh_c[h], bh_c[h], bh_c[h], bh_c[h]};
            az[h] = __builtin_amdgcn_mfma_f32_16x16x32_f16(ax, bz0[h], az[h], 0, 0, 0);
            az[h] = __builtin_amdgcn_mfma_f32_16x16x32_f16(at, bz1[h], az[h], 0, 0, 0);
            ah[h] = __builtin_amdgcn_mfma_f32_16x16x32_f16(ax, bh0[h], ah[h], 0, 0, 0);
            ah[h] = __builtin_amdgcn_mfma_f32_16x16x32_f16(at, bh1[h], ah[h], 0, 0, 0);
        }

        // epilogue: element j -> node tile0 + g*4 + j, feature col + 16h
        #pragma unroll
        for (int j = 0; j < 4; ++j) {
            float c = 0.0f;
            #pragma unroll
            for (int h = 0; h < 2; ++h) {
                float z  = 1.0f / (1.0f + __expf(-az[h][j]));
                float ht = tanhf(ah[h][j]);
                float hh = (1.0f - z) * ht;
                c += fmaxf(hh, 0.0f) * wl_c[h];
            }
            #pragma unroll
            for (int m = 8; m >= 1; m >>= 1) c += __shfl_xor(c, m, 64);
            int node = tile0 + g * 4 + j;
            if (col == 0 && node < N) out[node] = c + bl0;
        }
    }
}

extern "C" void kernel_launch(void* const* d_in, const int* in_sizes, int n_in,
                              void* d_out, int out_size, void* d_ws, size_t ws_size,
                              hipStream_t stream) {
    const float* x    = (const float*)d_in[0];
    const int*   edge = (const int*)d_in[1];   // [2, E]: src row then dst row
    const float* Wxz0 = (const float*)d_in[2];
    const float* Wxz1 = (const float*)d_in[3];
    const float* bxz  = (const float*)d_in[4];
    const float* bhz  = (const float*)d_in[7];
    const float* Wxh0 = (const float*)d_in[14];
    const float* Wxh1 = (const float*)d_in[15];
    const float* bxh  = (const float*)d_in[16];
    const float* bhh  = (const float*)d_in[19];
    const float* Wl   = (const float*)d_in[20];
    const float* bl   = (const float*)d_in[21];
    float* out = (float*)d_out;

    int N = in_sizes[0] / NF;
    int E = in_sizes[1] / 2;
    const int* src = edge;
    const int* dst = edge + E;

    // ws (4B elems): cnt[N] | acc[16N]
    int*          cnt = (int*)d_ws;
    unsigned int* acc = (unsigned int*)(cnt + N);

    hipMemsetAsync(cnt, 0, (size_t)N * sizeof(int), stream);

    int NT = N * 16;
    int cthreads = (E > NT) ? E : NT;
    count_kernel<<<(cthreads + 255) / 256, 256, 0, stream>>>(src, cnt, acc, E, NT);

    long long stt = (long long)E * 16;
    scatter_kernel<<<(int)((stt + 255) / 256), 256, 0, stream>>>(src, dst, cnt, x, acc, E);

    int ntiles = (N + 15) / 16;
    int gb = (ntiles + 3) / 4;
    if (gb > GATE_BLOCKS) gb = GATE_BLOCKS;
    gate_kernel<<<gb, 256, 0, stream>>>(
        x, (const unsigned short*)acc, cnt,
        Wxz0, Wxz1, bxz, bhz, Wxh0, Wxh1, bxh, bhh, Wl, bl, out, N);
}

// Round 13
// 169.831 us; speedup vs baseline: 1.0233x; 1.0233x over previous
//
#include <hip/hip_runtime.h>
#include <hip/hip_fp16.h>
#include <math.h>

#define NF 32

typedef _Float16 half8 __attribute__((ext_vector_type(8)));
typedef float f32x4 __attribute__((ext_vector_type(4)));

__device__ __forceinline__ void atomic_pk_add_f16(unsigned int* addr, unsigned int val) {
    asm volatile("global_atomic_pk_add_f16 %0, %1, off" :: "v"(addr), "v"(val) : "memory");
}

// ---- kernel 1: out-degree by src (for norm) --------------------------------
__global__ __launch_bounds__(256) void count_kernel(const int* __restrict__ src,
                                                    int* __restrict__ cnt, int E) {
    int e = blockIdx.x * blockDim.x + threadIdx.x;
    if (e < E) atomicAdd(&cnt[src[e]], 1);
}

// ---- kernel 2: scatter acc[dst] += f16x2(rsqrt(cnt[src]) * x[src]) ---------
// 25.6M pk-f16 atomics: measured ~291 G/s ~= 95% of the 307 G/s TCC ceiling.
__global__ __launch_bounds__(256) void scatter_kernel(
    const int* __restrict__ src, const int* __restrict__ dst,
    const int* __restrict__ cnt, const float* __restrict__ x,
    unsigned int* __restrict__ acc, int E) {
    int t = blockIdx.x * blockDim.x + threadIdx.x;
    int e = t >> 4;
    int f2 = t & 15;
    if (e >= E) return;
    int s = src[e];
    int d = dst[e];
    float di = rsqrtf((float)cnt[s]);
    float2 xv = *(const float2*)(x + (size_t)s * NF + f2 * 2);
    unsigned short lo = __half_as_ushort(__float2half(di * xv.x));
    unsigned short hi = __half_as_ushort(__float2half(di * xv.y));
    atomic_pk_add_f16(&acc[(size_t)d * 16 + f2], ((unsigned int)hi << 16) | lo);
}

// ---- kernel 3: MFMA gates + readout ----------------------------------------
// 256 threads = 4 waves; each wave owns a 16-node tile (block covers 64 nodes).
// az/ah tiles via mfma_f32_16x16x32_f16; weights in VGPR B-frags (no LDS).
__global__ __launch_bounds__(256) void gate_kernel(
    const float* __restrict__ x, const unsigned short* __restrict__ acc16,
    const int* __restrict__ cnt,
    const float* __restrict__ Wxz0, const float* __restrict__ Wxz1,
    const float* __restrict__ bxz,  const float* __restrict__ bhz,
    const float* __restrict__ Wxh0, const float* __restrict__ Wxh1,
    const float* __restrict__ bxh,  const float* __restrict__ bhh,
    const float* __restrict__ Wl,   const float* __restrict__ bl,
    float* __restrict__ out, int N)
{
    int lane = threadIdx.x & 63;
    int wv   = threadIdx.x >> 6;
    int col  = lane & 15;       // B-frag col / A-frag row index
    int g    = lane >> 4;       // k-group: this lane's k slots = g*8 .. g*8+7

    int tile0 = blockIdx.x * 64 + wv * 16;
    if (tile0 >= N) return;     // no __syncthreads in this kernel — safe

    // --- W fragments (per-lane, once per block): element e = W[g*8+e][col+16h]
    half8 bz0[2], bz1[2], bh0[2], bh1[2];
    #pragma unroll
    for (int h = 0; h < 2; ++h) {
        int c = col + 16 * h;
        #pragma unroll
        for (int e = 0; e < 8; ++e) {
            int k = g * 8 + e;
            bz0[h][e] = (_Float16)Wxz0[k * NF + c];
            bz1[h][e] = (_Float16)Wxz1[k * NF + c];
            bh0[h][e] = (_Float16)Wxh0[k * NF + c];
            bh1[h][e] = (_Float16)Wxh1[k * NF + c];
        }
    }
    float bz_c[2], bh_c[2], wl_c[2];
    #pragma unroll
    for (int h = 0; h < 2; ++h) {
        int c = col + 16 * h;
        bz_c[h] = bxz[c] + bhz[c];
        bh_c[h] = bxh[c] + bhh[c];
        wl_c[h] = Wl[c];
    }
    float bl0 = bl[0];

    // --- A fragments: row = tile0+col, k slots g*8..g*8+7
    int row = tile0 + col;
    int rc  = (row < N) ? row : (N - 1);
    const float* xr = x + (size_t)rc * NF + g * 8;
    float4 xa = *(const float4*)xr;
    float4 xb = *(const float4*)(xr + 4);
    half8 ax;
    ax[0] = (_Float16)xa.x; ax[1] = (_Float16)xa.y;
    ax[2] = (_Float16)xa.z; ax[3] = (_Float16)xa.w;
    ax[4] = (_Float16)xb.x; ax[5] = (_Float16)xb.y;
    ax[6] = (_Float16)xb.z; ax[7] = (_Float16)xb.w;

    int dg = cnt[rc];
    float mdn = (dg > 0) ? -rsqrtf((float)dg) : 0.0f;
    const unsigned short* ar = acc16 + (size_t)rc * NF + g * 8;
    uint4 av = *(const uint4*)ar;
    half8 at;
    {
        __half2 p;
        p = *(__half2*)&av.x; at[0] = (_Float16)(mdn * __half2float(p.x)); at[1] = (_Float16)(mdn * __half2float(p.y));
        p = *(__half2*)&av.y; at[2] = (_Float16)(mdn * __half2float(p.x)); at[3] = (_Float16)(mdn * __half2float(p.y));
        p = *(__half2*)&av.z; at[4] = (_Float16)(mdn * __half2float(p.x)); at[5] = (_Float16)(mdn * __half2float(p.y));
        p = *(__half2*)&av.w; at[6] = (_Float16)(mdn * __half2float(p.x)); at[7] = (_Float16)(mdn * __half2float(p.y));
    }

    // --- MFMAs: az = x@Wz0 + t@Wz1 + bias ; ah = x@Wh0 + t@Wh1 + bias -------
    f32x4 az[2], ah[2];
    #pragma unroll
    for (int h = 0; h < 2; ++h) {
        az[h] = (f32x4){bz_c[h], bz_c[h], bz_c[h], bz_c[h]};
        ah[h] = (f32x4){bh_c[h], bh_c[h], bh_c[h], bh_c[h]};
        az[h] = __builtin_amdgcn_mfma_f32_16x16x32_f16(ax, bz0[h], az[h], 0, 0, 0);
        az[h] = __builtin_amdgcn_mfma_f32_16x16x32_f16(at, bz1[h], az[h], 0, 0, 0);
        ah[h] = __builtin_amdgcn_mfma_f32_16x16x32_f16(ax, bh0[h], ah[h], 0, 0, 0);
        ah[h] = __builtin_amdgcn_mfma_f32_16x16x32_f16(at, bh1[h], ah[h], 0, 0, 0);
    }

    // --- epilogue: per element (node = tile0 + g*4 + j, f = col + 16h) ------
    #pragma unroll
    for (int j = 0; j < 4; ++j) {
        float c = 0.0f;
        #pragma unroll
        for (int h = 0; h < 2; ++h) {
            float z  = 1.0f / (1.0f + __expf(-az[h][j]));
            float ht = tanhf(ah[h][j]);
            float hh = (1.0f - z) * ht;
            c += fmaxf(hh, 0.0f) * wl_c[h];
        }
        // reduce over the 16 f-columns (lanes sharing g)
        #pragma unroll
        for (int m = 8; m >= 1; m >>= 1) c += __shfl_xor(c, m, 64);
        int node = tile0 + g * 4 + j;
        if (col == 0 && node < N) out[node] = c + bl0;
    }
}

extern "C" void kernel_launch(void* const* d_in, const int* in_sizes, int n_in,
                              void* d_out, int out_size, void* d_ws, size_t ws_size,
                              hipStream_t stream) {
    const float* x    = (const float*)d_in[0];
    const int*   edge = (const int*)d_in[1];   // [2, E]: src row then dst row
    const float* Wxz0 = (const float*)d_in[2];
    const float* Wxz1 = (const float*)d_in[3];
    const float* bxz  = (const float*)d_in[4];
    const float* bhz  = (const float*)d_in[7];
    const float* Wxh0 = (const float*)d_in[14];
    const float* Wxh1 = (const float*)d_in[15];
    const float* bxh  = (const float*)d_in[16];
    const float* bhh  = (const float*)d_in[19];
    const float* Wl   = (const float*)d_in[20];
    const float* bl   = (const float*)d_in[21];
    float* out = (float*)d_out;

    int N = in_sizes[0] / NF;
    int E = in_sizes[1] / 2;
    const int* src = edge;
    const int* dst = edge + E;

    // ws (4B elems): cnt[N] | acc[16N]  (both zeroed in one memset)
    int*          cnt = (int*)d_ws;
    unsigned int* acc = (unsigned int*)(cnt + N);

    hipMemsetAsync(d_ws, 0, (size_t)17 * N * sizeof(int), stream);

    count_kernel<<<(E + 255) / 256, 256, 0, stream>>>(src, cnt, E);

    long long stt = (long long)E * 16;
    scatter_kernel<<<(int)((stt + 255) / 256), 256, 0, stream>>>(src, dst, cnt, x, acc, E);

    gate_kernel<<<(N + 63) / 64, 256, 0, stream>>>(
        x, (const unsigned short*)acc, cnt,
        Wxz0, Wxz1, bxz, bhz, Wxh0, Wxh1, bxh, bhh, Wl, bl, out, N);
}